// Round 1
// baseline (329.019 us; speedup 1.0000x reference)
//
#include <hip/hip_runtime.h>
#include <math.h>

#define N_NODES 50000
#define N_EDGES 800000
#define F 128
#define ELL_CAP 128
#define ROWS_PER_BLOCK 64

// ---------------- transpose weights: Wt[k][j] = W[j][k] ----------------
__global__ void transpose_w(const float* __restrict__ W, float* __restrict__ Wt) {
    int idx = blockIdx.x * 256 + threadIdx.x;   // 0..16383
    if (idx < F * F) {
        int j = idx / F, k = idx % F;
        Wt[k * F + j] = W[j * F + k];
    }
}

// ---------------- build ELL adjacency (dst -> list of src) ----------------
__global__ void build_ell(const int* __restrict__ src, const int* __restrict__ dst,
                          int* __restrict__ cnt, int* __restrict__ nbr) {
    int e = blockIdx.x * 256 + threadIdx.x;
    if (e >= N_EDGES) return;
    int d = dst[e];
    int slot = atomicAdd(&cnt[d], 1);
    if (slot < ELL_CAP) nbr[d * ELL_CAP + slot] = src[e];
}

// ---------------- mean aggregation: one wave per destination node ----------------
__global__ __launch_bounds__(256) void aggregate(const float* __restrict__ X,
                                                 const int* __restrict__ cnt,
                                                 const int* __restrict__ nbr,
                                                 float* __restrict__ agg) {
    int wave = threadIdx.x >> 6;
    int lane = threadIdx.x & 63;
    int node = blockIdx.x * 4 + wave;
    if (node >= N_NODES) return;
    int degt = cnt[node];
    int deg = degt < ELL_CAP ? degt : ELL_CAP;
    const int* nb = nbr + (size_t)node * ELL_CAP;
    float2 acc0 = make_float2(0.f, 0.f);
    float2 acc1 = make_float2(0.f, 0.f);
    int s = 0;
    for (; s + 1 < deg; s += 2) {
        int v0 = nb[s];
        int v1 = nb[s + 1];
        float2 a = *(const float2*)(X + (size_t)v0 * F + lane * 2);
        float2 b = *(const float2*)(X + (size_t)v1 * F + lane * 2);
        acc0.x += a.x; acc0.y += a.y;
        acc1.x += b.x; acc1.y += b.y;
    }
    if (s < deg) {
        int v0 = nb[s];
        float2 a = *(const float2*)(X + (size_t)v0 * F + lane * 2);
        acc0.x += a.x; acc0.y += a.y;
    }
    float inv = 1.0f / (float)(degt > 0 ? degt : 1);
    float2 o = make_float2((acc0.x + acc1.x) * inv, (acc0.y + acc1.y) * inv);
    *(float2*)(agg + (size_t)node * F + lane * 2) = o;
}

// ---------------- fused SAGE layer GEMM: out = relu(A@Wl^T + b + B@Wr^T) ----------------
// A = aggregated rows, B = root rows. Wlt/Wrt are pre-transposed [k][j].
// out may alias A (each block stages its rows into LDS before writing them).
__global__ __launch_bounds__(256) void gemm_layer(const float* A, const float* B,
                                                  const float* __restrict__ Wlt,
                                                  const float* __restrict__ Wrt,
                                                  const float* __restrict__ bias,
                                                  float* outp, int relu) {
    __shared__ float sA[ROWS_PER_BLOCK * F];   // 32 KB
    __shared__ float sB[ROWS_PER_BLOCK * F];   // 32 KB
    int row0 = blockIdx.x * ROWS_PER_BLOCK;
    int t = threadIdx.x;

    // stage 64 rows of A and B (float4, coalesced)
    #pragma unroll
    for (int i = 0; i < 8; ++i) {
        int g = t + i * 256;          // float4 id, 0..2047
        int r = g >> 5;               // row in tile
        int kk = g & 31;              // float4 within row
        int row = row0 + r;
        float4 va = make_float4(0.f, 0.f, 0.f, 0.f);
        float4 vb = make_float4(0.f, 0.f, 0.f, 0.f);
        if (row < N_NODES) {
            va = *(const float4*)(A + (size_t)row * F + kk * 4);
            vb = *(const float4*)(B + (size_t)row * F + kk * 4);
        }
        *(float4*)(sA + r * F + kk * 4) = va;
        *(float4*)(sB + r * F + kk * 4) = vb;
    }
    __syncthreads();

    int lane = t & 63;
    int wave = t >> 6;
    int cg = lane >> 5;               // col-group (0/1)
    int c4 = (lane & 31) * 4;         // column base (0..124)
    int rbase = wave * 16 + cg * 8;   // 8 rows per thread

    float4 acc[8];
    #pragma unroll
    for (int r = 0; r < 8; ++r) acc[r] = make_float4(0.f, 0.f, 0.f, 0.f);

    for (int k0 = 0; k0 < F; k0 += 4) {
        float4 wl[4], wr[4];
        #pragma unroll
        for (int u = 0; u < 4; ++u) {
            wl[u] = *(const float4*)(Wlt + (k0 + u) * F + c4);
            wr[u] = *(const float4*)(Wrt + (k0 + u) * F + c4);
        }
        #pragma unroll
        for (int r = 0; r < 8; ++r) {
            float4 a4 = *(const float4*)(sA + (rbase + r) * F + k0);
            float4 b4 = *(const float4*)(sB + (rbase + r) * F + k0);
            float av[4] = {a4.x, a4.y, a4.z, a4.w};
            float bv[4] = {b4.x, b4.y, b4.z, b4.w};
            #pragma unroll
            for (int u = 0; u < 4; ++u) {
                acc[r].x += av[u] * wl[u].x + bv[u] * wr[u].x;
                acc[r].y += av[u] * wl[u].y + bv[u] * wr[u].y;
                acc[r].z += av[u] * wl[u].z + bv[u] * wr[u].z;
                acc[r].w += av[u] * wl[u].w + bv[u] * wr[u].w;
            }
        }
    }

    float4 bv = *(const float4*)(bias + c4);
    #pragma unroll
    for (int r = 0; r < 8; ++r) {
        int row = row0 + rbase + r;
        if (row < N_NODES) {
            float4 o;
            o.x = acc[r].x + bv.x;
            o.y = acc[r].y + bv.y;
            o.z = acc[r].z + bv.z;
            o.w = acc[r].w + bv.w;
            if (relu) {
                o.x = fmaxf(o.x, 0.f);
                o.y = fmaxf(o.y, 0.f);
                o.z = fmaxf(o.z, 0.f);
                o.w = fmaxf(o.w, 0.f);
            }
            *(float4*)(outp + (size_t)row * F + c4) = o;
        }
    }
}

// ---------------- head: logits = H@Wlin^T + blin, then log_softmax ----------------
__global__ __launch_bounds__(256) void head(const float* __restrict__ H,
                                            const float* __restrict__ Wlin,
                                            const float* __restrict__ blin,
                                            float* __restrict__ out) {
    int wave = threadIdx.x >> 6;
    int lane = threadIdx.x & 63;
    int row = blockIdx.x * 4 + wave;
    if (row >= N_NODES) return;
    const float* h = H + (size_t)row * F;
    float2 hv = *(const float2*)(h + lane * 2);
    float2 w0 = *(const float2*)(Wlin + lane * 2);
    float2 w1 = *(const float2*)(Wlin + F + lane * 2);
    float p0 = hv.x * w0.x + hv.y * w0.y;
    float p1 = hv.x * w1.x + hv.y * w1.y;
    #pragma unroll
    for (int off = 32; off; off >>= 1) {
        p0 += __shfl_xor(p0, off);
        p1 += __shfl_xor(p1, off);
    }
    if (lane == 0) {
        float a = p0 + blin[0];
        float b = p1 + blin[1];
        float m = fmaxf(a, b);
        float lse = m + logf(expf(a - m) + expf(b - m));
        out[(size_t)row * 2 + 0] = a - lse;
        out[(size_t)row * 2 + 1] = b - lse;
    }
}

extern "C" void kernel_launch(void* const* d_in, const int* in_sizes, int n_in,
                              void* d_out, int out_size, void* d_ws, size_t ws_size,
                              hipStream_t stream) {
    const float* x    = (const float*)d_in[0];
    const int*   ei   = (const int*)d_in[1];     // [2][N_EDGES] int32
    const float* W1l  = (const float*)d_in[2];
    const float* b1l  = (const float*)d_in[3];
    const float* W1r  = (const float*)d_in[4];
    const float* W2l  = (const float*)d_in[5];
    const float* b2l  = (const float*)d_in[6];
    const float* W2r  = (const float*)d_in[7];
    const float* Wlin = (const float*)d_in[8];
    const float* blin = (const float*)d_in[9];
    float* out = (float*)d_out;

    const int* src = ei;
    const int* dst = ei + N_EDGES;

    char* ws = (char*)d_ws;
    int*   cnt  = (int*)ws;                              // 200000 B
    int*   nbr  = (int*)(ws + 262144);                   // 25,600,000 B
    float* w1lt = (float*)(ws + 25862144);               // 4 x 65536 B
    float* w1rt = w1lt + F * F;
    float* w2lt = w1rt + F * F;
    float* w2rt = w2lt + F * F;
    float* agg  = (float*)(ws + 26124288);               // 25,600,000 B
    float* h1   = (float*)(ws + 51724288);               // 25,600,000 B

    hipMemsetAsync(cnt, 0, N_NODES * sizeof(int), stream);

    transpose_w<<<64, 256, 0, stream>>>(W1l, w1lt);
    transpose_w<<<64, 256, 0, stream>>>(W1r, w1rt);
    transpose_w<<<64, 256, 0, stream>>>(W2l, w2lt);
    transpose_w<<<64, 256, 0, stream>>>(W2r, w2rt);

    build_ell<<<3125, 256, 0, stream>>>(src, dst, cnt, nbr);

    // layer 1
    aggregate<<<12500, 256, 0, stream>>>(x, cnt, nbr, agg);
    gemm_layer<<<782, 256, 0, stream>>>(agg, x, w1lt, w1rt, b1l, h1, 1);

    // layer 2 (h2 aliases agg: block-private rows staged to LDS before overwrite)
    aggregate<<<12500, 256, 0, stream>>>(h1, cnt, nbr, agg);
    gemm_layer<<<782, 256, 0, stream>>>(agg, h1, w2lt, w2rt, b2l, agg, 1);

    // head
    head<<<12500, 256, 0, stream>>>(agg, Wlin, blin, out);
}

// Round 4
// 195.579 us; speedup vs baseline: 1.6823x; 1.6823x over previous
//
#include <hip/hip_runtime.h>
#include <math.h>

#define N_NODES 50000
#define N_EDGES 800000
#define F 128
#define ELL_CAP 128

typedef __attribute__((ext_vector_type(8))) short short8;
typedef __attribute__((ext_vector_type(4))) float float4v;

__device__ inline unsigned short f2bf(float f) {
    unsigned int u = __builtin_bit_cast(unsigned int, f);
    u += 0x7FFF + ((u >> 16) & 1);          // RNE
    return (unsigned short)(u >> 16);
}
__device__ inline float bf2f_lo(unsigned int u) {          // low ushort -> float
    return __builtin_bit_cast(float, u << 16);
}
__device__ inline float bf2f_hi(unsigned int u) {          // high ushort -> float
    return __builtin_bit_cast(float, u & 0xFFFF0000u);
}

// ---------------- fp32 -> bf16 bulk convert (x) ----------------
__global__ __launch_bounds__(256) void cvt_bf16(const float* __restrict__ in,
                                                unsigned short* __restrict__ outp) {
    int i = blockIdx.x * 256 + threadIdx.x;         // one float4 per thread
    float4 v = ((const float4*)in)[i];
    unsigned int p0 = (unsigned int)f2bf(v.x) | ((unsigned int)f2bf(v.y) << 16);
    unsigned int p1 = (unsigned int)f2bf(v.z) | ((unsigned int)f2bf(v.w) << 16);
    ((uint2*)outp)[i] = make_uint2(p0, p1);
}

// ---------------- pack [Wl;Wr] (each [128][128], row=out col=in) into MFMA B-frag order ----------------
// P[((ks*8+ct)*64 + lane)*8 + j] = Wcat[k = ks*32 + (lane>>4)*8 + j][col = ct*16 + (lane&15)]
// where Wcat rows 0..127 = Wl.T, 128..255 = Wr.T  (i.e. Wcat[k][c] = W[c][k])
__global__ __launch_bounds__(256) void pack_w(const float* __restrict__ Wl,
                                              const float* __restrict__ Wr,
                                              unsigned short* __restrict__ P) {
    int t = blockIdx.x * 256 + threadIdx.x;         // 0..4095
    if (t >= 4096) return;
    int lane = t & 63;
    int ct = (t >> 6) & 7;
    int ks = t >> 9;                                // 0..7
    int col = ct * 16 + (lane & 15);
    int kbase = (ks & 3) * 32 + (lane >> 4) * 8;
    const float* W = (ks < 4) ? Wl : Wr;
    unsigned short* dst = P + (size_t)t * 8;
    #pragma unroll
    for (int j = 0; j < 8; ++j) dst[j] = f2bf(W[col * F + kbase + j]);
}

// ---------------- build ELL adjacency (dst -> list of src) ----------------
__global__ void build_ell(const int* __restrict__ src, const int* __restrict__ dst,
                          int* __restrict__ cnt, int* __restrict__ nbr) {
    int e = blockIdx.x * 256 + threadIdx.x;
    if (e >= N_EDGES) return;
    int d = dst[e];
    int slot = atomicAdd(&cnt[d], 1);
    if (slot < ELL_CAP) nbr[d * ELL_CAP + slot] = src[e];
}

// ---------------- mean aggregation over bf16 rows: one wave per destination node ----------------
__global__ __launch_bounds__(256) void aggregate_bf(const unsigned short* __restrict__ X,
                                                    const int* __restrict__ cnt,
                                                    const int* __restrict__ nbr,
                                                    unsigned short* __restrict__ agg) {
    int wave = threadIdx.x >> 6;
    int lane = threadIdx.x & 63;
    int node = blockIdx.x * 4 + wave;
    if (node >= N_NODES) return;
    int degt = cnt[node];
    int deg = degt < ELL_CAP ? degt : ELL_CAP;
    const int* nb = nbr + (size_t)node * ELL_CAP;
    float a0 = 0.f, a1 = 0.f, b0 = 0.f, b1 = 0.f;
    int s = 0;
    for (; s + 1 < deg; s += 2) {
        int v0 = nb[s], v1 = nb[s + 1];
        unsigned int u0 = *(const unsigned int*)(X + (size_t)v0 * F + lane * 2);
        unsigned int u1 = *(const unsigned int*)(X + (size_t)v1 * F + lane * 2);
        a0 += bf2f_lo(u0); a1 += bf2f_hi(u0);
        b0 += bf2f_lo(u1); b1 += bf2f_hi(u1);
    }
    if (s < deg) {
        unsigned int u0 = *(const unsigned int*)(X + (size_t)nb[s] * F + lane * 2);
        a0 += bf2f_lo(u0); a1 += bf2f_hi(u0);
    }
    float inv = 1.0f / (float)(degt > 0 ? degt : 1);
    unsigned int p = (unsigned int)f2bf((a0 + b0) * inv) |
                     ((unsigned int)f2bf((a1 + b1) * inv) << 16);
    *(unsigned int*)(agg + (size_t)node * F + lane * 2) = p;
}

// ---------------- fused SAGE layer: relu([A|B] @ Wcat + bias), MFMA, no LDS ----------------
// mode 0: write bf16 Hout.  mode 1: fused classifier head + log_softmax -> out (fp32).
__global__ __launch_bounds__(256) void sage_gemm(const unsigned short* __restrict__ Abf,
                                                 const unsigned short* __restrict__ Bbf,
                                                 const unsigned short* __restrict__ Pw,
                                                 const float* __restrict__ bias,
                                                 unsigned short* __restrict__ Hout,
                                                 const float* __restrict__ Wlin,
                                                 const float* __restrict__ blin,
                                                 float* __restrict__ out, int mode) {
    int lane = threadIdx.x & 63;
    int wave = threadIdx.x >> 6;
    int r0 = blockIdx.x * 64 + wave * 16;
    int rowA = r0 + (lane & 15);
    if (rowA >= N_NODES) rowA = N_NODES - 1;        // clamp; writes are guarded
    int kg = lane >> 4;                             // k-group 0..3

    // A fragments: row = lane&15, k = ks*32 + kg*8 + j  (contiguous 16B)
    short8 af[4], bfr[4];
    const short8* Ap = (const short8*)(Abf + (size_t)rowA * F);
    const short8* Bp = (const short8*)(Bbf + (size_t)rowA * F);
    #pragma unroll
    for (int ks = 0; ks < 4; ++ks) {
        af[ks]  = Ap[ks * 4 + kg];
        bfr[ks] = Bp[ks * 4 + kg];
    }

    const short8* Wp = (const short8*)Pw;
    float4v acc[8];
    #pragma unroll
    for (int ct = 0; ct < 8; ++ct) {
        float4v c = {0.f, 0.f, 0.f, 0.f};
        #pragma unroll
        for (int ks = 0; ks < 4; ++ks)
            c = __builtin_amdgcn_mfma_f32_16x16x32_bf16(af[ks], Wp[(ks * 8 + ct) * 64 + lane], c, 0, 0, 0);
        #pragma unroll
        for (int ks = 0; ks < 4; ++ks)
            c = __builtin_amdgcn_mfma_f32_16x16x32_bf16(bfr[ks], Wp[((ks + 4) * 8 + ct) * 64 + lane], c, 0, 0, 0);
        acc[ct] = c;
    }

    int colb = lane & 15;
    int rq = lane >> 4;
    #pragma unroll
    for (int ct = 0; ct < 8; ++ct) {
        float bv = bias[ct * 16 + colb];
        #pragma unroll
        for (int i = 0; i < 4; ++i)
            acc[ct][i] = fmaxf(acc[ct][i] + bv, 0.f);
    }

    if (mode == 0) {
        #pragma unroll
        for (int ct = 0; ct < 8; ++ct) {
            #pragma unroll
            for (int i = 0; i < 4; ++i) {
                int row = r0 + rq * 4 + i;
                if (row < N_NODES)
                    Hout[(size_t)row * F + ct * 16 + colb] = f2bf(acc[ct][i]);
            }
        }
    } else {
        float w0[8], w1[8];
        #pragma unroll
        for (int ct = 0; ct < 8; ++ct) {
            w0[ct] = Wlin[ct * 16 + colb];
            w1[ct] = Wlin[F + ct * 16 + colb];
        }
        #pragma unroll
        for (int i = 0; i < 4; ++i) {
            float p0 = 0.f, p1 = 0.f;
            #pragma unroll
            for (int ct = 0; ct < 8; ++ct) {
                p0 += acc[ct][i] * w0[ct];
                p1 += acc[ct][i] * w1[ct];
            }
            #pragma unroll
            for (int off = 1; off < 16; off <<= 1) {
                p0 += __shfl_xor(p0, off);
                p1 += __shfl_xor(p1, off);
            }
            int row = r0 + rq * 4 + i;
            if (colb == 0 && row < N_NODES) {
                float a = p0 + blin[0];
                float b = p1 + blin[1];
                float m = fmaxf(a, b);
                float lse = m + logf(expf(a - m) + expf(b - m));
                out[(size_t)row * 2 + 0] = a - lse;
                out[(size_t)row * 2 + 1] = b - lse;
            }
        }
    }
}

extern "C" void kernel_launch(void* const* d_in, const int* in_sizes, int n_in,
                              void* d_out, int out_size, void* d_ws, size_t ws_size,
                              hipStream_t stream) {
    const float* x    = (const float*)d_in[0];
    const int*   ei   = (const int*)d_in[1];     // [2][N_EDGES] int32
    const float* W1l  = (const float*)d_in[2];
    const float* b1l  = (const float*)d_in[3];
    const float* W1r  = (const float*)d_in[4];
    const float* W2l  = (const float*)d_in[5];
    const float* b2l  = (const float*)d_in[6];
    const float* W2r  = (const float*)d_in[7];
    const float* Wlin = (const float*)d_in[8];
    const float* blin = (const float*)d_in[9];
    float* out = (float*)d_out;

    const int* src = ei;
    const int* dst = ei + N_EDGES;

    char* ws = (char*)d_ws;
    int*            cnt  = (int*)ws;                              // 200,000 B
    int*            nbr  = (int*)(ws + 262144);                   // 25.6 MB
    unsigned short* xb   = (unsigned short*)(ws + 25862144);      // 12.8 MB
    unsigned short* h1b  = (unsigned short*)(ws + 38662144);      // 12.8 MB
    unsigned short* aggb = (unsigned short*)(ws + 51462144);      // 12.8 MB
    unsigned short* P1   = (unsigned short*)(ws + 64262144);      // 64 KB
    unsigned short* P2   = (unsigned short*)(ws + 64327680);      // 64 KB

    hipMemsetAsync(cnt, 0, N_NODES * sizeof(int), stream);

    cvt_bf16<<<6250, 256, 0, stream>>>(x, xb);                    // 6.4M elems / 4
    pack_w<<<16, 256, 0, stream>>>(W1l, W1r, P1);
    pack_w<<<16, 256, 0, stream>>>(W2l, W2r, P2);
    build_ell<<<3125, 256, 0, stream>>>(src, dst, cnt, nbr);

    // layer 1
    aggregate_bf<<<12500, 256, 0, stream>>>(xb, cnt, nbr, aggb);
    sage_gemm<<<782, 256, 0, stream>>>(aggb, xb, P1, b1l, h1b, nullptr, nullptr, nullptr, 0);

    // layer 2 + fused head
    aggregate_bf<<<12500, 256, 0, stream>>>(h1b, cnt, nbr, aggb);
    sage_gemm<<<782, 256, 0, stream>>>(aggb, h1b, P2, b2l, nullptr, Wlin, blin, out, 1);
}